// Round 1
// baseline (903.003 us; speedup 1.0000x reference)
//
#include <hip/hip_runtime.h>

#define N_NODES 100000
#define IN_CH 128
#define HID 75
#define OUT_CH 40
#define N_EDGES 3200000
#define NCHUNKS 98  // ceil(100000/1024)

// ---------------- edge-index layout probe (int32 vs int64) ----------------
// If edge_index was delivered as int64, the int32 view is [v0,0,v1,0,...].
// Sample 256 high-words of src; all zero => int64 layout.
__global__ void probe64(const int* __restrict__ e, int* __restrict__ flag) {
    __shared__ int nonzero;
    if (threadIdx.x == 0) nonzero = 0;
    __syncthreads();
    int idx = threadIdx.x * 12497;              // < 3.2M
    if (e[2 * idx + 1] != 0) nonzero = 1;       // safe for both layouts
    __syncthreads();
    if (threadIdx.x == 0) *flag = (nonzero == 0) ? 1 : 0;
}

__global__ __launch_bounds__(256) void zero_deg(int* __restrict__ degI) {
    int i = blockIdx.x * 256 + threadIdx.x;
    if (i < N_NODES) degI[i] = 0;
}

__global__ __launch_bounds__(256) void count_deg(const int* __restrict__ e,
        const int* __restrict__ flag, int* __restrict__ degI) {
    int i = blockIdx.x * 256 + threadIdx.x;
    if (i >= N_EDGES) return;
    int d = (*flag) ? e[2 * (N_EDGES + i)] : e[N_EDGES + i];
    atomicAdd(&degI[d], 1);
}

__global__ __launch_bounds__(256) void compute_dinv(const int* __restrict__ degI,
        float* __restrict__ dinv) {
    int i = blockIdx.x * 256 + threadIdx.x;
    if (i < N_NODES) dinv[i] = rsqrtf((float)degI[i] + 1.0f);  // +1 self-loop
}

// ---------------- exclusive prefix sum of degI (3 kernels) ----------------
__global__ __launch_bounds__(256) void scan_a(const int* __restrict__ degI,
        int* __restrict__ chunkSums) {
    __shared__ int sh[256];
    int base = blockIdx.x * 1024 + threadIdx.x * 4;
    int s = 0;
    if (base < N_NODES) {
        int4 v = *reinterpret_cast<const int4*>(degI + base);
        s = v.x + v.y + v.z + v.w;
    }
    sh[threadIdx.x] = s;
    __syncthreads();
    for (int o = 128; o > 0; o >>= 1) {
        if (threadIdx.x < o) sh[threadIdx.x] += sh[threadIdx.x + o];
        __syncthreads();
    }
    if (threadIdx.x == 0) chunkSums[blockIdx.x] = sh[0];
}

__global__ __launch_bounds__(128) void scan_b(int* __restrict__ cs) {
    __shared__ int a[128], b[128];
    int tid = threadIdx.x;
    int v = (tid < NCHUNKS) ? cs[tid] : 0;
    a[tid] = v;
    __syncthreads();
    int* pin = a; int* pout = b;
    for (int o = 1; o < 128; o <<= 1) {
        int nv = pin[tid] + ((tid >= o) ? pin[tid - o] : 0);
        pout[tid] = nv;
        __syncthreads();
        int* t = pin; pin = pout; pout = t;
    }
    if (tid < NCHUNKS) cs[tid] = pin[tid] - v;   // exclusive
}

__global__ __launch_bounds__(256) void scan_c(const int* __restrict__ degI,
        const int* __restrict__ chunkSums, int* __restrict__ rowStart,
        int* __restrict__ cursor) {
    __shared__ int a[256], b[256];
    int tid = threadIdx.x;
    int base = blockIdx.x * 1024 + tid * 4;
    int4 v = make_int4(0, 0, 0, 0);
    if (base < N_NODES) v = *reinterpret_cast<const int4*>(degI + base);
    int tsum = v.x + v.y + v.z + v.w;
    a[tid] = tsum;
    __syncthreads();
    int* pin = a; int* pout = b;
    for (int o = 1; o < 256; o <<= 1) {
        int nv = pin[tid] + ((tid >= o) ? pin[tid - o] : 0);
        pout[tid] = nv;
        __syncthreads();
        int* t = pin; pin = pout; pout = t;
    }
    int excl = pin[tid] - tsum;
    if (base < N_NODES) {
        int p = chunkSums[blockIdx.x] + excl;
        rowStart[base + 0] = p; cursor[base + 0] = p; p += v.x;
        rowStart[base + 1] = p; cursor[base + 1] = p; p += v.y;
        rowStart[base + 2] = p; cursor[base + 2] = p; p += v.z;
        rowStart[base + 3] = p; cursor[base + 3] = p;
    }
    if (blockIdx.x == 0 && tid == 0) rowStart[N_NODES] = N_EDGES;
}

__global__ __launch_bounds__(256) void fill_csr(const int* __restrict__ e,
        const int* __restrict__ flag, int* __restrict__ cursor,
        int* __restrict__ csrSrc) {
    int i = blockIdx.x * 256 + threadIdx.x;
    if (i >= N_EDGES) return;
    int s, d;
    if (*flag) { s = e[2 * i]; d = e[2 * (N_EDGES + i)]; }
    else       { s = e[i];     d = e[N_EDGES + i]; }
    int pos = atomicAdd(&cursor[d], 1);
    csrSrc[pos] = s;
}

// ---------------- GEMM1: hs1 = dinv * (x @ W1)  [100000x128 @ 128x75] ------
__global__ __launch_bounds__(1024) void gemm1(const float* __restrict__ x,
        const float* __restrict__ W, const float* __restrict__ dinv,
        float* __restrict__ hs1) {
    __shared__ float Wl[IN_CH * HID];   // 38400 B
    for (int i = threadIdx.x; i < IN_CH * HID; i += 1024) Wl[i] = W[i];
    __syncthreads();
    int g = blockIdx.x * 1024 + threadIdx.x;
    if (g >= N_NODES * HID) return;
    int r = g / HID;
    int c = g - r * HID;
    const float4* xr = reinterpret_cast<const float4*>(x + r * IN_CH);
    float acc = 0.f;
#pragma unroll
    for (int k4 = 0; k4 < IN_CH / 4; ++k4) {
        float4 xv = xr[k4];
        int kb = k4 * 4;
        acc = fmaf(xv.x, Wl[(kb + 0) * HID + c], acc);
        acc = fmaf(xv.y, Wl[(kb + 1) * HID + c], acc);
        acc = fmaf(xv.z, Wl[(kb + 2) * HID + c], acc);
        acc = fmaf(xv.w, Wl[(kb + 3) * HID + c], acc);
    }
    hs1[g] = acc * dinv[r];
}

// ---------------- GEMM2: hs2 = dinv * (h1 @ W2)  [100000x75 @ 75x40] -------
__global__ __launch_bounds__(1024) void gemm2(const float* __restrict__ h1,
        const float* __restrict__ W, const float* __restrict__ dinv,
        float* __restrict__ hs2) {
    __shared__ float Wl[HID * OUT_CH];  // 12000 B
    for (int i = threadIdx.x; i < HID * OUT_CH; i += 1024) Wl[i] = W[i];
    __syncthreads();
    int g = blockIdx.x * 1024 + threadIdx.x;
    if (g >= N_NODES * OUT_CH) return;
    int r = g / OUT_CH;
    int c = g - r * OUT_CH;
    const float* hr = h1 + r * HID;
    float acc = 0.f;
#pragma unroll
    for (int k = 0; k < HID; ++k) acc = fmaf(hr[k], Wl[k * OUT_CH + c], acc);
    hs2[g] = acc * dinv[r];
}

// ---------------- aggregation: out[d] = f(dinv[d]*(sum_in hs[s] + hs[d]) + b)
// wave-per-node; lanes cover features (f and f+64). FINAL adds log_softmax.
template <int F, bool FINAL>
__global__ __launch_bounds__(256) void aggregate(
        const float* __restrict__ hs, const int* __restrict__ rowStart,
        const int* __restrict__ csrSrc, const float* __restrict__ dinv,
        const float* __restrict__ bias, float* __restrict__ out) {
    constexpr int F0V = (F < 64) ? F : 64;
    constexpr int F1V = (F > 64) ? (F - 64) : 0;
    int node = (blockIdx.x << 2) + (threadIdx.x >> 6);
    if (node >= N_NODES) return;
    int lane = threadIdx.x & 63;
    const float* hn = hs + (size_t)node * F;
    float acc0 = 0.f, acc1 = 0.f;
    if (lane < F0V) acc0 = hn[lane];                 // self-loop term
    if (F1V > 0 && lane < F1V) acc1 = hn[64 + lane];
    int j = rowStart[node];
    int end = rowStart[node + 1];
    for (; j + 4 <= end; j += 4) {
        int s0 = csrSrc[j], s1 = csrSrc[j + 1], s2 = csrSrc[j + 2], s3 = csrSrc[j + 3];
        const float* p0 = hs + (size_t)s0 * F;
        const float* p1 = hs + (size_t)s1 * F;
        const float* p2 = hs + (size_t)s2 * F;
        const float* p3 = hs + (size_t)s3 * F;
        if (lane < F0V) {
            acc0 += p0[lane]; acc0 += p1[lane]; acc0 += p2[lane]; acc0 += p3[lane];
        }
        if (F1V > 0 && lane < F1V) {
            acc1 += p0[64 + lane]; acc1 += p1[64 + lane];
            acc1 += p2[64 + lane]; acc1 += p3[64 + lane];
        }
    }
    for (; j < end; ++j) {
        const float* p = hs + (size_t)csrSrc[j] * F;
        if (lane < F0V) acc0 += p[lane];
        if (F1V > 0 && lane < F1V) acc1 += p[64 + lane];
    }
    float dn = dinv[node];
    if (!FINAL) {
        if (lane < F0V)
            out[(size_t)node * F + lane] = fmaxf(fmaf(dn, acc0, bias[lane]), 0.f);
        if (F1V > 0 && lane < F1V)
            out[(size_t)node * F + 64 + lane] = fmaxf(fmaf(dn, acc1, bias[64 + lane]), 0.f);
    } else {
        float v = (lane < F0V) ? fmaf(dn, acc0, bias[lane]) : -3.4e38f;
        float m = v;
#pragma unroll
        for (int o = 32; o > 0; o >>= 1) m = fmaxf(m, __shfl_xor(m, o));
        float e = (lane < F0V) ? __expf(v - m) : 0.f;
        float s = e;
#pragma unroll
        for (int o = 32; o > 0; o >>= 1) s += __shfl_xor(s, o);
        float lse = __logf(s);
        if (lane < F0V) out[(size_t)node * F + lane] = v - m - lse;
    }
}

extern "C" void kernel_launch(void* const* d_in, const int* in_sizes, int n_in,
                              void* d_out, int out_size, void* d_ws, size_t ws_size,
                              hipStream_t stream) {
    const float* x  = (const float*)d_in[0];
    const int*   e  = (const int*)d_in[1];
    const float* W1 = (const float*)d_in[2];
    const float* b1 = (const float*)d_in[3];
    const float* W2 = (const float*)d_in[4];
    const float* b2 = (const float*)d_in[5];
    float* out = (float*)d_out;

    // workspace carve (16B-aligned chunks)
    char* w = (char*)d_ws;
    float* hs1      = (float*)w; w += (size_t)N_NODES * HID * 4;   // 30 MB (reused as hs2)
    float* h1       = (float*)w; w += (size_t)N_NODES * HID * 4;   // 30 MB
    int*   csrSrc   = (int*)w;   w += (size_t)N_EDGES * 4;         // 12.8 MB
    int*   degI     = (int*)w;   w += N_NODES * 4;
    float* dinv     = (float*)w; w += N_NODES * 4;
    int*   rowStart = (int*)w;   w += 400016;                      // 100001 ints, padded
    int*   cursor   = (int*)w;   w += N_NODES * 4;
    int*   chunkSums= (int*)w;   w += 1024;
    int*   flag     = (int*)w;   w += 16;
    float* hs2      = hs1;                                         // alias (hs1 dead by then)

    probe64<<<1, 256, 0, stream>>>(e, flag);
    zero_deg<<<(N_NODES + 255) / 256, 256, 0, stream>>>(degI);
    count_deg<<<N_EDGES / 256, 256, 0, stream>>>(e, flag, degI);
    compute_dinv<<<(N_NODES + 255) / 256, 256, 0, stream>>>(degI, dinv);
    scan_a<<<NCHUNKS, 256, 0, stream>>>(degI, chunkSums);
    scan_b<<<1, 128, 0, stream>>>(chunkSums);
    scan_c<<<NCHUNKS, 256, 0, stream>>>(degI, chunkSums, rowStart, cursor);
    fill_csr<<<N_EDGES / 256, 256, 0, stream>>>(e, flag, cursor, csrSrc);

    gemm1<<<(N_NODES * HID + 1023) / 1024, 1024, 0, stream>>>(x, W1, dinv, hs1);
    aggregate<HID, false><<<(N_NODES + 3) / 4, 256, 0, stream>>>(
        hs1, rowStart, csrSrc, dinv, b1, h1);
    gemm2<<<(N_NODES * OUT_CH + 1023) / 1024, 1024, 0, stream>>>(h1, W2, dinv, hs2);
    aggregate<OUT_CH, true><<<(N_NODES + 3) / 4, 256, 0, stream>>>(
        hs2, rowStart, csrSrc, dinv, b2, out);
}

// Round 2
// 474.918 us; speedup vs baseline: 1.9014x; 1.9014x over previous
//
#include <hip/hip_runtime.h>

#define N_NODES 100000
#define IN_CH 128
#define HID 75
#define OUT_CH 40
#define N_EDGES 3200000

#define NB 196          // buckets of 512 dst nodes (195*512+160 = 100000)
#define CAP 20000       // per-bucket capacity; mean 16384, std ~128 -> 28 sigma
#define EPT 16          // edges per thread in passA
#define PA_EDGES (EPT * 256)

typedef unsigned short u16;

__device__ __forceinline__ float bf2f(u16 u) {
    return __uint_as_float(((unsigned)u) << 16);
}
__device__ __forceinline__ u16 f2bf(float f) {
    unsigned b = __float_as_uint(f);
    b += 0x7FFF + ((b >> 16) & 1);   // round-to-nearest-even
    return (u16)(b >> 16);
}

// ---------------- edge-index layout probe (int32 vs int64) ----------------
__global__ void probe64(const int* __restrict__ e, int* __restrict__ flag) {
    __shared__ int nonzero;
    if (threadIdx.x == 0) nonzero = 0;
    __syncthreads();
    int idx = threadIdx.x * 12497;              // < 3.2M
    if (e[2 * idx + 1] != 0) nonzero = 1;       // safe for both layouts
    __syncthreads();
    if (threadIdx.x == 0) *flag = (nonzero == 0) ? 1 : 0;
}

__global__ __launch_bounds__(256) void init_zero(int* __restrict__ bucketCursor) {
    int i = blockIdx.x * 256 + threadIdx.x;
    if (i < NB * 16) bucketCursor[i] = 0;
}

// ---------------- pass A: bin edges into 196 dst-range buckets ------------
__global__ __launch_bounds__(256) void passA(const int* __restrict__ e,
        const int* __restrict__ flag, int* __restrict__ bucketCursor,
        unsigned* __restrict__ bucketBuf) {
    __shared__ int cnt[NB];
    __shared__ int base[NB];
    int t = threadIdx.x;
    for (int i = t; i < NB; i += 256) cnt[i] = 0;
    __syncthreads();
    bool w64 = (*flag != 0);
    int s_[EPT], d_[EPT];
    int eb = blockIdx.x * PA_EDGES + t;
#pragma unroll
    for (int k = 0; k < EPT; ++k) {
        int idx = eb + k * 256;
        int s = 0, d = -1;
        if (idx < N_EDGES) {
            if (w64) { s = e[2 * idx]; d = e[2 * (N_EDGES + idx)]; }
            else     { s = e[idx];     d = e[N_EDGES + idx]; }
            atomicAdd(&cnt[d >> 9], 1);
        }
        s_[k] = s; d_[k] = d;
    }
    __syncthreads();
    for (int i = t; i < NB; i += 256) {
        int c = cnt[i];
        base[i] = (c > 0) ? atomicAdd(&bucketCursor[i * 16], c) : 0;  // 64B-padded cursors
        cnt[i] = 0;
    }
    __syncthreads();
#pragma unroll
    for (int k = 0; k < EPT; ++k) {
        int d = d_[k];
        if (d >= 0) {
            int b = d >> 9;
            int off = atomicAdd(&cnt[b], 1);
            int pos = base[b] + off;
            if (pos < CAP)
                bucketBuf[(size_t)b * CAP + pos] =
                    ((unsigned)(d & 511) << 17) | (unsigned)s_[k];
        }
    }
}

// ---------------- scan of 196 bucket sizes -> bucket starts ---------------
__global__ __launch_bounds__(256) void scan196(const int* __restrict__ bucketCursor,
        int* __restrict__ bucketStart, int* __restrict__ rowStart) {
    __shared__ int a[256], b[256];
    int t = threadIdx.x;
    int v = (t < NB) ? bucketCursor[t * 16] : 0;
    a[t] = v;
    __syncthreads();
    int* pin = a; int* pout = b;
    for (int o = 1; o < 256; o <<= 1) {
        int nv = pin[t] + ((t >= o) ? pin[t - o] : 0);
        pout[t] = nv;
        __syncthreads();
        int* tmp = pin; pin = pout; pout = tmp;
    }
    if (t < NB) bucketStart[t] = pin[t] - v;  // exclusive
    if (t == 0) rowStart[N_NODES] = N_EDGES;
}

// ---------------- pass B: per-bucket CSR fill, all atomics in LDS ---------
__global__ __launch_bounds__(1024) void passB(const unsigned* __restrict__ bucketBuf,
        const int* __restrict__ bucketCursor, const int* __restrict__ bucketStart,
        int* __restrict__ csrSrc, int* __restrict__ rowStart, float* __restrict__ dinv) {
    __shared__ int cnt[512];
    __shared__ int sa[512], sb[512];
    int b = blockIdx.x;
    int t = threadIdx.x;
    int n = bucketCursor[b * 16];
    int start = bucketStart[b];
    if (t < 512) cnt[t] = 0;
    __syncthreads();
    const unsigned* buf = bucketBuf + (size_t)b * CAP;
    for (int i = t; i < n; i += 1024) atomicAdd(&cnt[buf[i] >> 17], 1);
    __syncthreads();
    if (t < 512) sa[t] = cnt[t];
    __syncthreads();
    int* pin = sa; int* pout = sb;
    for (int o = 1; o < 512; o <<= 1) {
        if (t < 512) pout[t] = pin[t] + ((t >= o) ? pin[t - o] : 0);
        __syncthreads();
        int* tmp = pin; pin = pout; pout = tmp;
    }
    int excl = 0;
    if (t < 512) {
        int deg = cnt[t];
        excl = pin[t] - deg;
        int node = b * 512 + t;
        if (node < N_NODES) {
            rowStart[node] = start + excl;
            dinv[node] = rsqrtf((float)deg + 1.0f);  // +1 self-loop
        }
    }
    __syncthreads();
    if (t < 512) cnt[t] = excl;   // LDS cursors
    __syncthreads();
    for (int i = t; i < n; i += 1024) {
        unsigned p = buf[i];
        int pos = atomicAdd(&cnt[p >> 17], 1);
        csrSrc[start + pos] = (int)(p & 0x1FFFF);
    }
}

// ---------------- GEMM1: hs1 = bf16( dinv * (x @ W1) ), row stride 96 -----
__global__ __launch_bounds__(1024) void gemm1(const float* __restrict__ x,
        const float* __restrict__ W, const float* __restrict__ dinv,
        u16* __restrict__ hs1) {
    __shared__ float Wl[IN_CH * HID];
    for (int i = threadIdx.x; i < IN_CH * HID; i += 1024) Wl[i] = W[i];
    __syncthreads();
    int g = blockIdx.x * 1024 + threadIdx.x;
    if (g >= N_NODES * HID) return;
    int r = g / HID;
    int c = g - r * HID;
    const float4* xr = reinterpret_cast<const float4*>(x + r * IN_CH);
    float acc = 0.f;
#pragma unroll
    for (int k4 = 0; k4 < IN_CH / 4; ++k4) {
        float4 xv = xr[k4];
        int kb = k4 * 4;
        acc = fmaf(xv.x, Wl[(kb + 0) * HID + c], acc);
        acc = fmaf(xv.y, Wl[(kb + 1) * HID + c], acc);
        acc = fmaf(xv.z, Wl[(kb + 2) * HID + c], acc);
        acc = fmaf(xv.w, Wl[(kb + 3) * HID + c], acc);
    }
    hs1[(size_t)r * 96 + c] = f2bf(acc * dinv[r]);
}

// ---------------- GEMM2: hs2 = bf16( dinv * (h1 @ W2) ), row stride 48 ----
__global__ __launch_bounds__(1024) void gemm2(const float* __restrict__ h1,
        const float* __restrict__ W, const float* __restrict__ dinv,
        u16* __restrict__ hs2) {
    __shared__ float Wl[HID * OUT_CH];
    for (int i = threadIdx.x; i < HID * OUT_CH; i += 1024) Wl[i] = W[i];
    __syncthreads();
    int g = blockIdx.x * 1024 + threadIdx.x;
    if (g >= N_NODES * OUT_CH) return;
    int r = g / OUT_CH;
    int c = g - r * OUT_CH;
    const float* hr = h1 + (size_t)r * HID;
    float acc = 0.f;
#pragma unroll
    for (int k = 0; k < HID; ++k) acc = fmaf(hr[k], Wl[k * OUT_CH + c], acc);
    hs2[(size_t)r * 48 + c] = f2bf(acc * dinv[r]);
}

// ---------------- aggregation over CSR (bf16 tables, f32 accum) -----------
template <int F, int STRIDE, bool FINAL>
__global__ __launch_bounds__(256) void aggregate(
        const u16* __restrict__ hs, const int* __restrict__ rowStart,
        const int* __restrict__ csrSrc, const float* __restrict__ dinv,
        const float* __restrict__ bias, float* __restrict__ out) {
    constexpr int F0V = (F < 64) ? F : 64;
    constexpr int F1V = (F > 64) ? (F - 64) : 0;
    int node = (blockIdx.x << 2) + (threadIdx.x >> 6);
    if (node >= N_NODES) return;
    int lane = threadIdx.x & 63;
    const u16* hn = hs + (size_t)node * STRIDE;
    float acc0 = 0.f, acc1 = 0.f;
    if (lane < F0V) acc0 = bf2f(hn[lane]);                 // self-loop term
    if (F1V > 0 && lane < F1V) acc1 = bf2f(hn[64 + lane]);
    int j = rowStart[node];
    int end = rowStart[node + 1];
    for (; j + 8 <= end; j += 8) {
        const u16* p[8];
#pragma unroll
        for (int q = 0; q < 8; ++q) p[q] = hs + (size_t)csrSrc[j + q] * STRIDE;
        if (lane < F0V) {
#pragma unroll
            for (int q = 0; q < 8; ++q) acc0 += bf2f(p[q][lane]);
        }
        if (F1V > 0 && lane < F1V) {
#pragma unroll
            for (int q = 0; q < 8; ++q) acc1 += bf2f(p[q][64 + lane]);
        }
    }
    for (; j < end; ++j) {
        const u16* p = hs + (size_t)csrSrc[j] * STRIDE;
        if (lane < F0V) acc0 += bf2f(p[lane]);
        if (F1V > 0 && lane < F1V) acc1 += bf2f(p[64 + lane]);
    }
    float dn = dinv[node];
    if (!FINAL) {
        if (lane < F0V)
            out[(size_t)node * F + lane] = fmaxf(fmaf(dn, acc0, bias[lane]), 0.f);
        if (F1V > 0 && lane < F1V)
            out[(size_t)node * F + 64 + lane] = fmaxf(fmaf(dn, acc1, bias[64 + lane]), 0.f);
    } else {
        float v = (lane < F0V) ? fmaf(dn, acc0, bias[lane]) : -3.4e38f;
        float m = v;
#pragma unroll
        for (int o = 32; o > 0; o >>= 1) m = fmaxf(m, __shfl_xor(m, o));
        float e = (lane < F0V) ? expf(v - m) : 0.f;
        float s = e;
#pragma unroll
        for (int o = 32; o > 0; o >>= 1) s += __shfl_xor(s, o);
        float lse = logf(s);
        if (lane < F0V) out[(size_t)node * F + lane] = v - m - lse;
    }
}

extern "C" void kernel_launch(void* const* d_in, const int* in_sizes, int n_in,
                              void* d_out, int out_size, void* d_ws, size_t ws_size,
                              hipStream_t stream) {
    const float* x  = (const float*)d_in[0];
    const int*   e  = (const int*)d_in[1];
    const float* W1 = (const float*)d_in[2];
    const float* b1 = (const float*)d_in[3];
    const float* W2 = (const float*)d_in[4];
    const float* b2 = (const float*)d_in[5];
    float* out = (float*)d_out;

    // workspace carve (all regions 16B aligned); total ~72.4 MB
    char* w = (char*)d_ws;
    unsigned* bucketBuf = (unsigned*)w;          // 15.68 MB, dead after passB
    u16*      hs1       = (u16*)w;               // 19.2 MB, aliases bucketBuf
    w += 19200000;
    float* h1        = (float*)w; w += 30000000; // 100000*75*4
    int*   csrSrc    = (int*)w;   w += 12800000;
    u16*   hs2       = (u16*)w;   w += 9600000;  // 100000*48*2
    int*   rowStart  = (int*)w;   w += 400016;
    float* dinv      = (float*)w; w += 400000;
    int*   bucketCursor = (int*)w; w += NB * 16 * 4;  // 64B-padded cursors
    int*   bucketStart  = (int*)w; w += 1024;
    int*   flag      = (int*)w;   w += 16;

    probe64<<<1, 256, 0, stream>>>(e, flag);
    init_zero<<<(NB * 16 + 255) / 256, 256, 0, stream>>>(bucketCursor);
    passA<<<(N_EDGES + PA_EDGES - 1) / PA_EDGES, 256, 0, stream>>>(
        e, flag, bucketCursor, bucketBuf);
    scan196<<<1, 256, 0, stream>>>(bucketCursor, bucketStart, rowStart);
    passB<<<NB, 1024, 0, stream>>>(bucketBuf, bucketCursor, bucketStart,
                                   csrSrc, rowStart, dinv);

    gemm1<<<(N_NODES * HID + 1023) / 1024, 1024, 0, stream>>>(x, W1, dinv, hs1);
    aggregate<HID, 96, false><<<(N_NODES + 3) / 4, 256, 0, stream>>>(
        hs1, rowStart, csrSrc, dinv, b1, h1);
    gemm2<<<(N_NODES * OUT_CH + 1023) / 1024, 1024, 0, stream>>>(h1, W2, dinv, hs2);
    aggregate<OUT_CH, 48, true><<<(N_NODES + 3) / 4, 256, 0, stream>>>(
        hs2, rowStart, csrSrc, dinv, b2, out);
}

// Round 3
// 329.572 us; speedup vs baseline: 2.7399x; 1.4410x over previous
//
#include <hip/hip_runtime.h>

#define N_NODES 100000
#define IN_CH 128
#define HID 75
#define OUT_CH 40
#define N_EDGES 3200000

#define NB 196          // buckets of 512 dst nodes
#define CAP 20000       // per-bucket capacity; mean 16384
#define EPT 16          // edges per thread in passA
#define PA_EDGES (EPT * 256)

typedef unsigned short u16;
typedef unsigned int u32;
typedef short short8 __attribute__((ext_vector_type(8)));
typedef float f32x4 __attribute__((ext_vector_type(4)));

__device__ __forceinline__ float bf2f(u16 u) {
    return __uint_as_float(((u32)u) << 16);
}
__device__ __forceinline__ u16 f2bf(float f) {
    u32 b = __float_as_uint(f);
    b += 0x7FFF + ((b >> 16) & 1);   // round-to-nearest-even
    return (u16)(b >> 16);
}

// ---------------- edge-index layout probe (int32 vs int64) ----------------
__global__ void probe64(const int* __restrict__ e, int* __restrict__ flag) {
    __shared__ int nonzero;
    if (threadIdx.x == 0) nonzero = 0;
    __syncthreads();
    int idx = threadIdx.x * 12497;              // < 3.2M
    if (e[2 * idx + 1] != 0) nonzero = 1;       // safe for both layouts
    __syncthreads();
    if (threadIdx.x == 0) *flag = (nonzero == 0) ? 1 : 0;
}

__global__ __launch_bounds__(256) void init_zero(int* __restrict__ bucketCursor) {
    int i = blockIdx.x * 256 + threadIdx.x;
    if (i < NB * 16) bucketCursor[i] = 0;
}

// ---------------- pass A: bin edges into 196 dst-range buckets ------------
__global__ __launch_bounds__(256) void passA(const int* __restrict__ e,
        const int* __restrict__ flag, int* __restrict__ bucketCursor,
        unsigned* __restrict__ bucketBuf) {
    __shared__ int cnt[NB];
    __shared__ int base[NB];
    int t = threadIdx.x;
    for (int i = t; i < NB; i += 256) cnt[i] = 0;
    __syncthreads();
    bool w64 = (*flag != 0);
    int s_[EPT], d_[EPT];
    int eb = blockIdx.x * PA_EDGES + t;
#pragma unroll
    for (int k = 0; k < EPT; ++k) {
        int idx = eb + k * 256;
        int s = 0, d = -1;
        if (idx < N_EDGES) {
            if (w64) { s = e[2 * idx]; d = e[2 * (N_EDGES + idx)]; }
            else     { s = e[idx];     d = e[N_EDGES + idx]; }
            atomicAdd(&cnt[d >> 9], 1);
        }
        s_[k] = s; d_[k] = d;
    }
    __syncthreads();
    for (int i = t; i < NB; i += 256) {
        int c = cnt[i];
        base[i] = (c > 0) ? atomicAdd(&bucketCursor[i * 16], c) : 0;  // 64B-padded cursors
        cnt[i] = 0;
    }
    __syncthreads();
#pragma unroll
    for (int k = 0; k < EPT; ++k) {
        int d = d_[k];
        if (d >= 0) {
            int b = d >> 9;
            int off = atomicAdd(&cnt[b], 1);
            int pos = base[b] + off;
            if (pos < CAP)
                bucketBuf[(size_t)b * CAP + pos] =
                    ((unsigned)(d & 511) << 17) | (unsigned)s_[k];
        }
    }
}

// ---------------- scan of 196 bucket sizes -> bucket starts ---------------
__global__ __launch_bounds__(256) void scan196(const int* __restrict__ bucketCursor,
        int* __restrict__ bucketStart, int* __restrict__ rowStart) {
    __shared__ int a[256], b[256];
    int t = threadIdx.x;
    int v = (t < NB) ? bucketCursor[t * 16] : 0;
    a[t] = v;
    __syncthreads();
    int* pin = a; int* pout = b;
    for (int o = 1; o < 256; o <<= 1) {
        int nv = pin[t] + ((t >= o) ? pin[t - o] : 0);
        pout[t] = nv;
        __syncthreads();
        int* tmp = pin; pin = pout; pout = tmp;
    }
    if (t < NB) bucketStart[t] = pin[t] - v;  // exclusive
    if (t == 0) rowStart[N_NODES] = N_EDGES;
}

// ---------------- pass B: per-bucket CSR fill, all atomics in LDS ---------
__global__ __launch_bounds__(1024) void passB(const unsigned* __restrict__ bucketBuf,
        const int* __restrict__ bucketCursor, const int* __restrict__ bucketStart,
        int* __restrict__ csrSrc, int* __restrict__ rowStart, float* __restrict__ dinv) {
    __shared__ int cnt[512];
    __shared__ int sa[512], sb[512];
    int b = blockIdx.x;
    int t = threadIdx.x;
    int n = bucketCursor[b * 16];
    int start = bucketStart[b];
    if (t < 512) cnt[t] = 0;
    __syncthreads();
    const unsigned* buf = bucketBuf + (size_t)b * CAP;
    for (int i = t; i < n; i += 1024) atomicAdd(&cnt[buf[i] >> 17], 1);
    __syncthreads();
    if (t < 512) sa[t] = cnt[t];
    __syncthreads();
    int* pin = sa; int* pout = sb;
    for (int o = 1; o < 512; o <<= 1) {
        if (t < 512) pout[t] = pin[t] + ((t >= o) ? pin[t - o] : 0);
        __syncthreads();
        int* tmp = pin; pin = pout; pout = tmp;
    }
    int excl = 0;
    if (t < 512) {
        int deg = cnt[t];
        excl = pin[t] - deg;
        int node = b * 512 + t;
        if (node < N_NODES) {
            rowStart[node] = start + excl;
            dinv[node] = rsqrtf((float)deg + 1.0f);  // +1 self-loop
        }
    }
    __syncthreads();
    if (t < 512) cnt[t] = excl;   // LDS cursors
    __syncthreads();
    for (int i = t; i < n; i += 1024) {
        unsigned p = buf[i];
        int pos = atomicAdd(&cnt[p >> 17], 1);
        csrSrc[start + pos] = (int)(p & 0x1FFFF);
    }
}

// ---------------- prep: bf16 transposed weights ---------------------------
// w1t[80][128]: w1t[c][k] = W1[k][c] (c<75), else 0
// w2t[48][96] : w2t[c][k] = W2[k][c] (c<40,k<75), else 0
__global__ __launch_bounds__(256) void prep_w(const float* __restrict__ W1,
        const float* __restrict__ W2, u16* __restrict__ w1t, u16* __restrict__ w2t) {
    int g = blockIdx.x * 256 + threadIdx.x;
    int stride = gridDim.x * 256;
    for (int i = g; i < 80 * 128; i += stride) {
        int c = i >> 7, k = i & 127;
        w1t[i] = (c < HID) ? f2bf(W1[k * HID + c]) : (u16)0;
    }
    for (int i = g; i < 48 * 96; i += stride) {
        int c = i / 96, k = i - c * 96;
        w2t[i] = (c < OUT_CH && k < HID) ? f2bf(W2[k * OUT_CH + c]) : (u16)0;
    }
}

// ---------------- GEMM1 via MFMA: hs1 = bf16(dinv * (x @ W1)), stride 96 --
// block: 4 waves x 16 rows = 64 rows; N=80 (5 col-tiles); K=128 (4 k-steps)
__global__ __launch_bounds__(256) void gemm1_mfma(const float* __restrict__ x,
        const u16* __restrict__ w1t, const float* __restrict__ dinv,
        u16* __restrict__ hs1) {
    __shared__ u16 Wl[80 * 136];   // pad 128->136 elems: bank-spread rows
    int t = threadIdx.x;
    {
        const u32* ws = (const u32*)w1t;
        u32* wd = (u32*)Wl;
        for (int i = t; i < 80 * 64; i += 256) {
            int r = i >> 6, c = i & 63;
            wd[r * 68 + c] = ws[i];
        }
    }
    __syncthreads();
    int wid = t >> 6, lane = t & 63;
    int bl = lane & 15, kh = lane >> 4;
    int row0 = blockIdx.x * 64 + wid * 16;
    // B fragments in registers: b[j] = W1t-row(col)[k0 + 8*kh + j] (contiguous)
    short8 bf[5][4];
#pragma unroll
    for (int ct = 0; ct < 5; ++ct)
#pragma unroll
        for (int ks = 0; ks < 4; ++ks)
            bf[ct][ks] = *(const short8*)&Wl[(ct * 16 + bl) * 136 + ks * 32 + kh * 8];
    f32x4 zero = {0.f, 0.f, 0.f, 0.f};
    f32x4 acc[5];
#pragma unroll
    for (int ct = 0; ct < 5; ++ct) acc[ct] = zero;
    int arow = row0 + bl;
    bool av = (arow < N_NODES);
    const float* xr = x + (size_t)arow * IN_CH + kh * 8;
#pragma unroll
    for (int ks = 0; ks < 4; ++ks) {
        short8 af = {0, 0, 0, 0, 0, 0, 0, 0};
        if (av) {
            float4 lo = *(const float4*)(xr + ks * 32);
            float4 hi = *(const float4*)(xr + ks * 32 + 4);
            af[0] = (short)f2bf(lo.x); af[1] = (short)f2bf(lo.y);
            af[2] = (short)f2bf(lo.z); af[3] = (short)f2bf(lo.w);
            af[4] = (short)f2bf(hi.x); af[5] = (short)f2bf(hi.y);
            af[6] = (short)f2bf(hi.z); af[7] = (short)f2bf(hi.w);
        }
#pragma unroll
        for (int ct = 0; ct < 5; ++ct)
            acc[ct] = __builtin_amdgcn_mfma_f32_16x16x32_bf16(af, bf[ct][ks], acc[ct], 0, 0, 0);
    }
    // C/D: col = lane&15, row = (lane>>4)*4 + reg  [HW-verified]
    int orow = row0 + kh * 4;
    float dn[4];
#pragma unroll
    for (int i = 0; i < 4; ++i) dn[i] = (orow + i < N_NODES) ? dinv[orow + i] : 0.f;
#pragma unroll
    for (int ct = 0; ct < 5; ++ct) {
        int col = ct * 16 + bl;
#pragma unroll
        for (int i = 0; i < 4; ++i) {
            int r = orow + i;
            if (r < N_NODES) hs1[(size_t)r * 96 + col] = f2bf(acc[ct][i] * dn[i]);
        }
    }
}

// ---------------- GEMM2 via MFMA: hs2 = bf16(dinv * (h1 @ W2)), stride 48 -
// K = 96 (75 zero-padded), N = 48 (40 zero-padded); 3x3 tiles
__global__ __launch_bounds__(256) void gemm2_mfma(const u16* __restrict__ h1b,
        const u16* __restrict__ w2t, const float* __restrict__ dinv,
        u16* __restrict__ hs2) {
    __shared__ u16 Wl[48 * 104];   // pad 96->104
    int t = threadIdx.x;
    {
        const u32* ws = (const u32*)w2t;
        u32* wd = (u32*)Wl;
        for (int i = t; i < 48 * 48; i += 256) {
            int r = i / 48, c = i - r * 48;
            wd[r * 52 + c] = ws[i];
        }
    }
    __syncthreads();
    int wid = t >> 6, lane = t & 63;
    int bl = lane & 15, kh = lane >> 4;
    int row0 = blockIdx.x * 64 + wid * 16;
    short8 bf[3][3];
#pragma unroll
    for (int ct = 0; ct < 3; ++ct)
#pragma unroll
        for (int ks = 0; ks < 3; ++ks)
            bf[ct][ks] = *(const short8*)&Wl[(ct * 16 + bl) * 104 + ks * 32 + kh * 8];
    f32x4 zero = {0.f, 0.f, 0.f, 0.f};
    f32x4 acc[3];
#pragma unroll
    for (int ct = 0; ct < 3; ++ct) acc[ct] = zero;
    int arow = row0 + bl;
    bool av = (arow < N_NODES);
    const u16* hr = h1b + (size_t)arow * 96 + kh * 8;
#pragma unroll
    for (int ks = 0; ks < 3; ++ks) {
        short8 af = {0, 0, 0, 0, 0, 0, 0, 0};
        if (av) af = *(const short8*)(hr + ks * 32);
#pragma unroll
        for (int ct = 0; ct < 3; ++ct)
            acc[ct] = __builtin_amdgcn_mfma_f32_16x16x32_bf16(af, bf[ct][ks], acc[ct], 0, 0, 0);
    }
    int orow = row0 + kh * 4;
    float dn[4];
#pragma unroll
    for (int i = 0; i < 4; ++i) dn[i] = (orow + i < N_NODES) ? dinv[orow + i] : 0.f;
#pragma unroll
    for (int ct = 0; ct < 3; ++ct) {
        int col = ct * 16 + bl;
#pragma unroll
        for (int i = 0; i < 4; ++i) {
            int r = orow + i;
            if (r < N_NODES) hs2[(size_t)r * 48 + col] = f2bf(acc[ct][i] * dn[i]);
        }
    }
}

// ---------------- aggregation layer 1: bf16 in (stride 96) -> bf16 out ----
// out = relu(dinv*(sum + self) + b), written bf16 stride 96, pad cols zeroed
__global__ __launch_bounds__(256) void aggregate1(
        const u16* __restrict__ hs, const int* __restrict__ rowStart,
        const int* __restrict__ csrSrc, const float* __restrict__ dinv,
        const float* __restrict__ bias, u16* __restrict__ out) {
    int node = (blockIdx.x << 2) + (threadIdx.x >> 6);
    if (node >= N_NODES) return;
    int lane = threadIdx.x & 63;
    const u16* hn = hs + (size_t)node * 96;
    float acc0 = 0.f, acc1 = 0.f;
    acc0 = bf2f(hn[lane]);                       // self-loop (cols 0..63)
    if (lane < 11) acc1 = bf2f(hn[64 + lane]);   // cols 64..74
    int j = rowStart[node];
    int end = rowStart[node + 1];
    for (; j + 8 <= end; j += 8) {
        const u16* p[8];
#pragma unroll
        for (int q = 0; q < 8; ++q) p[q] = hs + (size_t)csrSrc[j + q] * 96;
#pragma unroll
        for (int q = 0; q < 8; ++q) acc0 += bf2f(p[q][lane]);
        if (lane < 11) {
#pragma unroll
            for (int q = 0; q < 8; ++q) acc1 += bf2f(p[q][64 + lane]);
        }
    }
    for (; j < end; ++j) {
        const u16* p = hs + (size_t)csrSrc[j] * 96;
        acc0 += bf2f(p[lane]);
        if (lane < 11) acc1 += bf2f(p[64 + lane]);
    }
    float dn = dinv[node];
    u16* o = out + (size_t)node * 96;
    o[lane] = f2bf(fmaxf(fmaf(dn, acc0, bias[lane]), 0.f));
    if (lane < 11) o[64 + lane] = f2bf(fmaxf(fmaf(dn, acc1, bias[64 + lane]), 0.f));
    else if (lane < 32) o[64 + lane] = 0;        // zero pad cols 75..95 (gemm2 K-pad)
}

// ---------------- aggregation layer 2 + log_softmax: bf16 in -> f32 out ---
__global__ __launch_bounds__(256) void aggregate2(
        const u16* __restrict__ hs, const int* __restrict__ rowStart,
        const int* __restrict__ csrSrc, const float* __restrict__ dinv,
        const float* __restrict__ bias, float* __restrict__ out) {
    int node = (blockIdx.x << 2) + (threadIdx.x >> 6);
    if (node >= N_NODES) return;
    int lane = threadIdx.x & 63;
    const u16* hn = hs + (size_t)node * 48;
    float acc0 = 0.f;
    if (lane < OUT_CH) acc0 = bf2f(hn[lane]);    // self-loop
    int j = rowStart[node];
    int end = rowStart[node + 1];
    for (; j + 8 <= end; j += 8) {
        const u16* p[8];
#pragma unroll
        for (int q = 0; q < 8; ++q) p[q] = hs + (size_t)csrSrc[j + q] * 48;
        if (lane < OUT_CH) {
#pragma unroll
            for (int q = 0; q < 8; ++q) acc0 += bf2f(p[q][lane]);
        }
    }
    for (; j < end; ++j) {
        const u16* p = hs + (size_t)csrSrc[j] * 48;
        if (lane < OUT_CH) acc0 += bf2f(p[lane]);
    }
    float dn = dinv[node];
    float v = (lane < OUT_CH) ? fmaf(dn, acc0, bias[lane]) : -3.4e38f;
    float m = v;
#pragma unroll
    for (int o = 32; o > 0; o >>= 1) m = fmaxf(m, __shfl_xor(m, o));
    float e = (lane < OUT_CH) ? expf(v - m) : 0.f;
    float s = e;
#pragma unroll
    for (int o = 32; o > 0; o >>= 1) s += __shfl_xor(s, o);
    float lse = logf(s);
    if (lane < OUT_CH) out[(size_t)node * OUT_CH + lane] = v - m - lse;
}

extern "C" void kernel_launch(void* const* d_in, const int* in_sizes, int n_in,
                              void* d_out, int out_size, void* d_ws, size_t ws_size,
                              hipStream_t stream) {
    const float* x  = (const float*)d_in[0];
    const int*   e  = (const int*)d_in[1];
    const float* W1 = (const float*)d_in[2];
    const float* b1 = (const float*)d_in[3];
    const float* W2 = (const float*)d_in[4];
    const float* b2 = (const float*)d_in[5];
    float* out = (float*)d_out;

    // workspace carve (all sizes multiples of 16 B); total ~61.3 MB
    char* w = (char*)d_ws;
    unsigned* bucketBuf = (unsigned*)w;              // 15.68 MB, dead after passB
    u16* hs1  = (u16*)w; w += (size_t)100032 * 96 * 2;   // 19.2 MB (aliases bucketBuf)
    u16* h1b  = (u16*)w; w += (size_t)100032 * 96 * 2;   // 19.2 MB
    int* csrSrc = (int*)w; w += (size_t)N_EDGES * 4;     // 12.8 MB
    u16* hs2  = (u16*)w; w += (size_t)100000 * 48 * 2;   // 9.6 MB
    int* rowStart = (int*)w; w += 400016;
    float* dinv   = (float*)w; w += 400000;
    int* bucketCursor = (int*)w; w += NB * 16 * 4;
    int* bucketStart  = (int*)w; w += 1024;
    u16* w1t = (u16*)w; w += 80 * 128 * 2;
    u16* w2t = (u16*)w; w += 48 * 96 * 2;
    int* flag = (int*)w; w += 16;

    probe64<<<1, 256, 0, stream>>>(e, flag);
    init_zero<<<(NB * 16 + 255) / 256, 256, 0, stream>>>(bucketCursor);
    passA<<<(N_EDGES + PA_EDGES - 1) / PA_EDGES, 256, 0, stream>>>(
        e, flag, bucketCursor, bucketBuf);
    scan196<<<1, 256, 0, stream>>>(bucketCursor, bucketStart, rowStart);
    passB<<<NB, 1024, 0, stream>>>(bucketBuf, bucketCursor, bucketStart,
                                   csrSrc, rowStart, dinv);
    prep_w<<<16, 256, 0, stream>>>(W1, W2, w1t, w2t);

    gemm1_mfma<<<(N_NODES + 63) / 64, 256, 0, stream>>>(x, w1t, dinv, hs1);
    aggregate1<<<(N_NODES + 3) / 4, 256, 0, stream>>>(
        hs1, rowStart, csrSrc, dinv, b1, h1b);
    gemm2_mfma<<<(N_NODES + 63) / 64, 256, 0, stream>>>(h1b, w2t, dinv, hs2);
    aggregate2<<<(N_NODES + 3) / 4, 256, 0, stream>>>(
        hs2, rowStart, csrSrc, dinv, b2, out);
}

// Round 4
// 306.665 us; speedup vs baseline: 2.9446x; 1.0747x over previous
//
#include <hip/hip_runtime.h>

#define N_NODES 100000
#define IN_CH 128
#define HID 75
#define OUT_CH 40
#define N_EDGES 3200000

#define NB 196          // buckets of 512 dst nodes
#define CAP 20000       // per-bucket capacity; mean 16384
#define EPT 16          // edges per thread in passA
#define PA_EDGES (EPT * 256)

typedef unsigned short u16;
typedef unsigned int u32;
typedef short short8 __attribute__((ext_vector_type(8)));
typedef float f32x4 __attribute__((ext_vector_type(4)));

__device__ __forceinline__ float bf2f(u16 u) {
    return __uint_as_float(((u32)u) << 16);
}
__device__ __forceinline__ u16 f2bf(float f) {
    u32 b = __float_as_uint(f);
    b += 0x7FFF + ((b >> 16) & 1);   // round-to-nearest-even
    return (u16)(b >> 16);
}

// ---------------- edge-index layout probe (int32 vs int64) ----------------
__global__ void probe64(const int* __restrict__ e, int* __restrict__ flag) {
    __shared__ int nonzero;
    if (threadIdx.x == 0) nonzero = 0;
    __syncthreads();
    int idx = threadIdx.x * 12497;              // < 3.2M
    if (e[2 * idx + 1] != 0) nonzero = 1;       // safe for both layouts
    __syncthreads();
    if (threadIdx.x == 0) *flag = (nonzero == 0) ? 1 : 0;
}

__global__ __launch_bounds__(256) void init_zero(int* __restrict__ bucketCursor) {
    int i = blockIdx.x * 256 + threadIdx.x;
    if (i < NB * 16) bucketCursor[i] = 0;
}

// ---------------- pass A: bin edges into 196 dst-range buckets ------------
__global__ __launch_bounds__(256) void passA(const int* __restrict__ e,
        const int* __restrict__ flag, int* __restrict__ bucketCursor,
        unsigned* __restrict__ bucketBuf) {
    __shared__ int cnt[NB];
    __shared__ int base[NB];
    int t = threadIdx.x;
    for (int i = t; i < NB; i += 256) cnt[i] = 0;
    __syncthreads();
    bool w64 = (*flag != 0);
    int s_[EPT], d_[EPT];
    int eb = blockIdx.x * PA_EDGES + t;
#pragma unroll
    for (int k = 0; k < EPT; ++k) {
        int idx = eb + k * 256;
        int s = 0, d = -1;
        if (idx < N_EDGES) {
            if (w64) { s = e[2 * idx]; d = e[2 * (N_EDGES + idx)]; }
            else     { s = e[idx];     d = e[N_EDGES + idx]; }
            atomicAdd(&cnt[d >> 9], 1);
        }
        s_[k] = s; d_[k] = d;
    }
    __syncthreads();
    for (int i = t; i < NB; i += 256) {
        int c = cnt[i];
        base[i] = (c > 0) ? atomicAdd(&bucketCursor[i * 16], c) : 0;  // 64B-padded cursors
        cnt[i] = 0;
    }
    __syncthreads();
#pragma unroll
    for (int k = 0; k < EPT; ++k) {
        int d = d_[k];
        if (d >= 0) {
            int b = d >> 9;
            int off = atomicAdd(&cnt[b], 1);
            int pos = base[b] + off;
            if (pos < CAP)
                bucketBuf[(size_t)b * CAP + pos] =
                    ((unsigned)(d & 511) << 17) | (unsigned)s_[k];
        }
    }
}

// ---------------- scan of 196 bucket sizes -> bucket starts ---------------
__global__ __launch_bounds__(256) void scan196(const int* __restrict__ bucketCursor,
        int* __restrict__ bucketStart, int* __restrict__ rowStart) {
    __shared__ int a[256], b[256];
    int t = threadIdx.x;
    int v = (t < NB) ? bucketCursor[t * 16] : 0;
    a[t] = v;
    __syncthreads();
    int* pin = a; int* pout = b;
    for (int o = 1; o < 256; o <<= 1) {
        int nv = pin[t] + ((t >= o) ? pin[t - o] : 0);
        pout[t] = nv;
        __syncthreads();
        int* tmp = pin; pin = pout; pout = tmp;
    }
    if (t < NB) bucketStart[t] = pin[t] - v;  // exclusive
    if (t == 0) rowStart[N_NODES] = N_EDGES;
}

// ---------------- pass B: per-bucket CSR fill, all atomics in LDS ---------
__global__ __launch_bounds__(1024) void passB(const unsigned* __restrict__ bucketBuf,
        const int* __restrict__ bucketCursor, const int* __restrict__ bucketStart,
        int* __restrict__ csrSrc, int* __restrict__ rowStart, float* __restrict__ dinv) {
    __shared__ int cnt[512];
    __shared__ int sa[512], sb[512];
    int b = blockIdx.x;
    int t = threadIdx.x;
    int n = bucketCursor[b * 16];
    int start = bucketStart[b];
    if (t < 512) cnt[t] = 0;
    __syncthreads();
    const unsigned* buf = bucketBuf + (size_t)b * CAP;
    for (int i = t; i < n; i += 1024) atomicAdd(&cnt[buf[i] >> 17], 1);
    __syncthreads();
    if (t < 512) sa[t] = cnt[t];
    __syncthreads();
    int* pin = sa; int* pout = sb;
    for (int o = 1; o < 512; o <<= 1) {
        if (t < 512) pout[t] = pin[t] + ((t >= o) ? pin[t - o] : 0);
        __syncthreads();
        int* tmp = pin; pin = pout; pout = tmp;
    }
    int excl = 0;
    if (t < 512) {
        int deg = cnt[t];
        excl = pin[t] - deg;
        int node = b * 512 + t;
        if (node < N_NODES) {
            rowStart[node] = start + excl;
            dinv[node] = rsqrtf((float)deg + 1.0f);  // +1 self-loop
        }
    }
    __syncthreads();
    if (t < 512) cnt[t] = excl;   // LDS cursors
    __syncthreads();
    for (int i = t; i < n; i += 1024) {
        unsigned p = buf[i];
        int pos = atomicAdd(&cnt[p >> 17], 1);
        csrSrc[start + pos] = (int)(p & 0x1FFFF);
    }
}

// ---------------- prep: bf16 transposed weights ---------------------------
__global__ __launch_bounds__(256) void prep_w(const float* __restrict__ W1,
        const float* __restrict__ W2, u16* __restrict__ w1t, u16* __restrict__ w2t) {
    int g = blockIdx.x * 256 + threadIdx.x;
    int stride = gridDim.x * 256;
    for (int i = g; i < 80 * 128; i += stride) {
        int c = i >> 7, k = i & 127;
        w1t[i] = (c < HID) ? f2bf(W1[k * HID + c]) : (u16)0;
    }
    for (int i = g; i < 48 * 96; i += stride) {
        int c = i / 96, k = i - c * 96;
        w2t[i] = (c < OUT_CH && k < HID) ? f2bf(W2[k * OUT_CH + c]) : (u16)0;
    }
}

// ---------------- GEMM1 via MFMA: hs1 = bf16(dinv * (x @ W1)), stride 96 --
__global__ __launch_bounds__(256) void gemm1_mfma(const float* __restrict__ x,
        const u16* __restrict__ w1t, const float* __restrict__ dinv,
        u16* __restrict__ hs1) {
    __shared__ u16 Wl[80 * 136];   // pad 128->136 elems: bank-spread rows
    int t = threadIdx.x;
    {
        const u32* ws = (const u32*)w1t;
        u32* wd = (u32*)Wl;
        for (int i = t; i < 80 * 64; i += 256) {
            int r = i >> 6, c = i & 63;
            wd[r * 68 + c] = ws[i];
        }
    }
    __syncthreads();
    int wid = t >> 6, lane = t & 63;
    int bl = lane & 15, kh = lane >> 4;
    int row0 = blockIdx.x * 64 + wid * 16;
    short8 bf[5][4];
#pragma unroll
    for (int ct = 0; ct < 5; ++ct)
#pragma unroll
        for (int ks = 0; ks < 4; ++ks)
            bf[ct][ks] = *(const short8*)&Wl[(ct * 16 + bl) * 136 + ks * 32 + kh * 8];
    f32x4 zero = {0.f, 0.f, 0.f, 0.f};
    f32x4 acc[5];
#pragma unroll
    for (int ct = 0; ct < 5; ++ct) acc[ct] = zero;
    int arow = row0 + bl;
    bool av = (arow < N_NODES);
    const float* xr = x + (size_t)arow * IN_CH + kh * 8;
#pragma unroll
    for (int ks = 0; ks < 4; ++ks) {
        short8 af = {0, 0, 0, 0, 0, 0, 0, 0};
        if (av) {
            float4 lo = *(const float4*)(xr + ks * 32);
            float4 hi = *(const float4*)(xr + ks * 32 + 4);
            af[0] = (short)f2bf(lo.x); af[1] = (short)f2bf(lo.y);
            af[2] = (short)f2bf(lo.z); af[3] = (short)f2bf(lo.w);
            af[4] = (short)f2bf(hi.x); af[5] = (short)f2bf(hi.y);
            af[6] = (short)f2bf(hi.z); af[7] = (short)f2bf(hi.w);
        }
#pragma unroll
        for (int ct = 0; ct < 5; ++ct)
            acc[ct] = __builtin_amdgcn_mfma_f32_16x16x32_bf16(af, bf[ct][ks], acc[ct], 0, 0, 0);
    }
    // C/D: col = lane&15, row = (lane>>4)*4 + reg  [HW-verified]
    int orow = row0 + kh * 4;
    float dn[4];
#pragma unroll
    for (int i = 0; i < 4; ++i) dn[i] = (orow + i < N_NODES) ? dinv[orow + i] : 0.f;
#pragma unroll
    for (int ct = 0; ct < 5; ++ct) {
        int col = ct * 16 + bl;
#pragma unroll
        for (int i = 0; i < 4; ++i) {
            int r = orow + i;
            if (r < N_NODES) hs1[(size_t)r * 96 + col] = f2bf(acc[ct][i] * dn[i]);
        }
    }
}

// ---------------- GEMM2 via MFMA: hs2 = bf16(dinv * (h1 @ W2)), stride 48 -
__global__ __launch_bounds__(256) void gemm2_mfma(const u16* __restrict__ h1b,
        const u16* __restrict__ w2t, const float* __restrict__ dinv,
        u16* __restrict__ hs2) {
    __shared__ u16 Wl[48 * 104];   // pad 96->104
    int t = threadIdx.x;
    {
        const u32* ws = (const u32*)w2t;
        u32* wd = (u32*)Wl;
        for (int i = t; i < 48 * 48; i += 256) {
            int r = i / 48, c = i - r * 48;
            wd[r * 52 + c] = ws[i];
        }
    }
    __syncthreads();
    int wid = t >> 6, lane = t & 63;
    int bl = lane & 15, kh = lane >> 4;
    int row0 = blockIdx.x * 64 + wid * 16;
    short8 bf[3][3];
#pragma unroll
    for (int ct = 0; ct < 3; ++ct)
#pragma unroll
        for (int ks = 0; ks < 3; ++ks)
            bf[ct][ks] = *(const short8*)&Wl[(ct * 16 + bl) * 104 + ks * 32 + kh * 8];
    f32x4 zero = {0.f, 0.f, 0.f, 0.f};
    f32x4 acc[3];
#pragma unroll
    for (int ct = 0; ct < 3; ++ct) acc[ct] = zero;
    int arow = row0 + bl;
    bool av = (arow < N_NODES);
    const u16* hr = h1b + (size_t)arow * 96 + kh * 8;
#pragma unroll
    for (int ks = 0; ks < 3; ++ks) {
        short8 af = {0, 0, 0, 0, 0, 0, 0, 0};
        if (av) af = *(const short8*)(hr + ks * 32);
#pragma unroll
        for (int ct = 0; ct < 3; ++ct)
            acc[ct] = __builtin_amdgcn_mfma_f32_16x16x32_bf16(af, bf[ct][ks], acc[ct], 0, 0, 0);
    }
    int orow = row0 + kh * 4;
    float dn[4];
#pragma unroll
    for (int i = 0; i < 4; ++i) dn[i] = (orow + i < N_NODES) ? dinv[orow + i] : 0.f;
#pragma unroll
    for (int ct = 0; ct < 3; ++ct) {
        int col = ct * 16 + bl;
#pragma unroll
        for (int i = 0; i < 4; ++i) {
            int r = orow + i;
            if (r < N_NODES) hs2[(size_t)r * 48 + col] = f2bf(acc[ct][i] * dn[i]);
        }
    }
}

// ---------------- aggregation layer 1: u32-packed bf16 gather -------------
// tab = hs1 rows of 48 u32 (96 bf16). 1 VMEM gather/edge (48 lanes), indices
// scalarized to the SMEM pipe via readfirstlane(node). Output u32-packed.
__global__ __launch_bounds__(256) void aggregate1(
        const u32* __restrict__ tab, const int* __restrict__ rowStart,
        const int* __restrict__ csrSrc, const float* __restrict__ dinv,
        const float* __restrict__ bias, u32* __restrict__ out) {
    int wid = threadIdx.x >> 6;
    int lane = threadIdx.x & 63;
    int node = __builtin_amdgcn_readfirstlane(blockIdx.x * 4 + wid);
    if (node >= N_NODES) return;
    bool act = lane < 48;
    float accLo = 0.f, accHi = 0.f;
    if (act) {
        u32 v = tab[(size_t)node * 48 + lane];        // self-loop term
        accLo = __uint_as_float(v << 16);
        accHi = __uint_as_float(v & 0xFFFF0000u);
    }
    int j = rowStart[node];
    int end = rowStart[node + 1];
    for (; j + 8 <= end; j += 8) {
        u32 v[8];
#pragma unroll
        for (int q = 0; q < 8; ++q) {
            int idx = csrSrc[j + q];                  // uniform -> s_load
            v[q] = act ? tab[(size_t)idx * 48 + lane] : 0u;
        }
#pragma unroll
        for (int q = 0; q < 8; ++q) {
            accLo += __uint_as_float(v[q] << 16);
            accHi += __uint_as_float(v[q] & 0xFFFF0000u);
        }
    }
    for (; j < end; ++j) {
        int idx = csrSrc[j];
        u32 v = act ? tab[(size_t)idx * 48 + lane] : 0u;
        accLo += __uint_as_float(v << 16);
        accHi += __uint_as_float(v & 0xFFFF0000u);
    }
    float dn = dinv[node];
    int c0 = 2 * lane, c1 = 2 * lane + 1;
    float blo = (c0 < HID) ? bias[c0] : 0.f;
    float bhi = (c1 < HID) ? bias[c1] : 0.f;
    float rlo = (c0 < HID) ? fmaxf(fmaf(dn, accLo, blo), 0.f) : 0.f;
    float rhi = (c1 < HID) ? fmaxf(fmaf(dn, accHi, bhi), 0.f) : 0.f;
    if (act)
        out[(size_t)node * 48 + lane] = ((u32)f2bf(rhi) << 16) | (u32)f2bf(rlo);
}

// ---------------- aggregation layer 2 + log_softmax -----------------------
// tab = hs2 rows of 24 u32 (48 bf16), 20 active lanes (40 features).
__global__ __launch_bounds__(256) void aggregate2(
        const u32* __restrict__ tab, const int* __restrict__ rowStart,
        const int* __restrict__ csrSrc, const float* __restrict__ dinv,
        const float* __restrict__ bias, float* __restrict__ out) {
    int wid = threadIdx.x >> 6;
    int lane = threadIdx.x & 63;
    int node = __builtin_amdgcn_readfirstlane(blockIdx.x * 4 + wid);
    if (node >= N_NODES) return;
    bool act = lane < 20;
    float accLo = 0.f, accHi = 0.f;
    if (act) {
        u32 v = tab[(size_t)node * 24 + lane];        // self-loop term
        accLo = __uint_as_float(v << 16);
        accHi = __uint_as_float(v & 0xFFFF0000u);
    }
    int j = rowStart[node];
    int end = rowStart[node + 1];
    for (; j + 8 <= end; j += 8) {
        u32 v[8];
#pragma unroll
        for (int q = 0; q < 8; ++q) {
            int idx = csrSrc[j + q];                  // uniform -> s_load
            v[q] = act ? tab[(size_t)idx * 24 + lane] : 0u;
        }
#pragma unroll
        for (int q = 0; q < 8; ++q) {
            accLo += __uint_as_float(v[q] << 16);
            accHi += __uint_as_float(v[q] & 0xFFFF0000u);
        }
    }
    for (; j < end; ++j) {
        int idx = csrSrc[j];
        u32 v = act ? tab[(size_t)idx * 24 + lane] : 0u;
        accLo += __uint_as_float(v << 16);
        accHi += __uint_as_float(v & 0xFFFF0000u);
    }
    float dn = dinv[node];
    float vlo = 0.f, vhi = 0.f, m = -3.4e38f;
    if (act) {
        vlo = fmaf(dn, accLo, bias[2 * lane]);
        vhi = fmaf(dn, accHi, bias[2 * lane + 1]);
        m = fmaxf(vlo, vhi);
    }
#pragma unroll
    for (int o = 32; o > 0; o >>= 1) m = fmaxf(m, __shfl_xor(m, o));
    float e = act ? (expf(vlo - m) + expf(vhi - m)) : 0.f;
#pragma unroll
    for (int o = 32; o > 0; o >>= 1) e += __shfl_xor(e, o);
    float lse = logf(e);
    if (act) {
        float2 r = make_float2(vlo - m - lse, vhi - m - lse);
        *reinterpret_cast<float2*>(out + (size_t)node * OUT_CH + 2 * lane) = r;
    }
}

extern "C" void kernel_launch(void* const* d_in, const int* in_sizes, int n_in,
                              void* d_out, int out_size, void* d_ws, size_t ws_size,
                              hipStream_t stream) {
    const float* x  = (const float*)d_in[0];
    const int*   e  = (const int*)d_in[1];
    const float* W1 = (const float*)d_in[2];
    const float* b1 = (const float*)d_in[3];
    const float* W2 = (const float*)d_in[4];
    const float* b2 = (const float*)d_in[5];
    float* out = (float*)d_out;

    // workspace carve (all sizes multiples of 16 B); total ~61.3 MB
    char* w = (char*)d_ws;
    unsigned* bucketBuf = (unsigned*)w;              // 15.68 MB, dead after passB
    u16* hs1  = (u16*)w; w += (size_t)100032 * 96 * 2;   // 19.2 MB (aliases bucketBuf)
    u16* h1b  = (u16*)w; w += (size_t)100032 * 96 * 2;   // 19.2 MB
    int* csrSrc = (int*)w; w += (size_t)N_EDGES * 4;     // 12.8 MB
    u16* hs2  = (u16*)w; w += (size_t)100000 * 48 * 2;   // 9.6 MB
    int* rowStart = (int*)w; w += 400016;
    float* dinv   = (float*)w; w += 400000;
    int* bucketCursor = (int*)w; w += NB * 16 * 4;
    int* bucketStart  = (int*)w; w += 1024;
    u16* w1t = (u16*)w; w += 80 * 128 * 2;
    u16* w2t = (u16*)w; w += 48 * 96 * 2;
    int* flag = (int*)w; w += 16;

    probe64<<<1, 256, 0, stream>>>(e, flag);
    init_zero<<<(NB * 16 + 255) / 256, 256, 0, stream>>>(bucketCursor);
    passA<<<(N_EDGES + PA_EDGES - 1) / PA_EDGES, 256, 0, stream>>>(
        e, flag, bucketCursor, bucketBuf);
    scan196<<<1, 256, 0, stream>>>(bucketCursor, bucketStart, rowStart);
    passB<<<NB, 1024, 0, stream>>>(bucketBuf, bucketCursor, bucketStart,
                                   csrSrc, rowStart, dinv);
    prep_w<<<16, 256, 0, stream>>>(W1, W2, w1t, w2t);

    gemm1_mfma<<<(N_NODES + 63) / 64, 256, 0, stream>>>(x, w1t, dinv, hs1);
    aggregate1<<<(N_NODES + 3) / 4, 256, 0, stream>>>(
        (const u32*)hs1, rowStart, csrSrc, dinv, b1, (u32*)h1b);
    gemm2_mfma<<<(N_NODES + 63) / 64, 256, 0, stream>>>(h1b, w2t, dinv, hs2);
    aggregate2<<<(N_NODES + 3) / 4, 256, 0, stream>>>(
        (const u32*)hs2, rowStart, csrSrc, dinv, b2, out);
}